// Round 5
// baseline (714.632 us; speedup 1.0000x reference)
//
#include <hip/hip_runtime.h>

#define NN 20000
#define NE 320000
#define EPN (NE + NN)   // edges + self loops = 340000
#define NH 4
#define NC 64
#define RP_STRIDE 20004
#define DCAP 64         // per-(node,type) degree cap for LDS-cached fast path

// ---------------- CSR build ----------------
__global__ void k_init_counts(int* __restrict__ cnt) {
  int i = blockIdx.x * blockDim.x + threadIdx.x;
  if (i < 4 * NN) cnt[i] = 1;   // self loop
}

__global__ void k_count(const int* __restrict__ d0, const int* __restrict__ d1,
                        const int* __restrict__ d2, const int* __restrict__ d3,
                        int* __restrict__ cnt) {
  int i = blockIdx.x * blockDim.x + threadIdx.x;
  if (i >= 4 * NE) return;
  int t = i / NE, e = i - t * NE;
  const int* d = t == 0 ? d0 : t == 1 ? d1 : t == 2 ? d2 : d3;
  atomicAdd(&cnt[t * NN + d[e]], 1);
}

__global__ void k_scan(const int* __restrict__ cnt, int* __restrict__ rp, int* __restrict__ tmp) {
  int t = blockIdx.x;
  const int* c = cnt + t * NN;
  int* r = rp + t * RP_STRIDE;
  int* tm = tmp + t * NN;
  __shared__ int part[256];
  int tid = threadIdx.x;
  const int CH = (NN + 255) / 256;
  int lo = tid * CH, hi = min(lo + CH, NN);
  int s = 0;
  for (int i = lo; i < hi; i++) s += c[i];
  part[tid] = s;
  __syncthreads();
  if (tid == 0) {
    int run = 0;
    for (int i = 0; i < 256; i++) { int v = part[i]; part[i] = run; run += v; }
  }
  __syncthreads();
  int run = part[tid];
  for (int i = lo; i < hi; i++) { r[i] = run; tm[i] = run; run += c[i]; }
  if (lo < NN && hi == NN) r[NN] = run;
}

__global__ void k_fill(const int* __restrict__ e0, const int* __restrict__ e1,
                       const int* __restrict__ e2, const int* __restrict__ e3,
                       int* __restrict__ tmp, int* __restrict__ col) {
  int i = blockIdx.x * blockDim.x + threadIdx.x;
  if (i >= 4 * EPN) return;
  int t = i / EPN, j = i - t * EPN;
  const int* eb = t == 0 ? e0 : t == 1 ? e1 : t == 2 ? e2 : e3;
  int s, d;
  if (j < NE) { s = eb[j]; d = eb[NE + j]; } else { s = d = j - NE; }
  int pos = atomicAdd(&tmp[t * NN + d], 1);
  col[(size_t)t * EPN + pos] = s;
}

// ---------------- fused GEMM + attention-coefficient epilogue ----------------
template <int K, int RM>
__global__ __launch_bounds__(256) void k_gemm_attn(
    const float* __restrict__ A, const float* __restrict__ W,
    const float* __restrict__ a_s, const float* __restrict__ a_d,
    float* __restrict__ H, float* __restrict__ asrc, float* __restrict__ adst,
    int colbase, int hstride) {
  constexpr int BM = RM * 16;
  __shared__ float As[32][BM + 4];
  __shared__ float Bs[32][132];
  int tid = threadIdx.x;
  int row0 = blockIdx.x * BM;
  int hcolb = blockIdx.y << 7;
  int gc0 = colbase + hcolb;                 // global fused column (0..1023)
  int t = gc0 >> 8, wc = gc0 & 255;
  const float* WB = W + (size_t)t * K * 256 + wc;
  int tx = tid & 15, ra = tid >> 4;
  int kc_a = (tid & 7) << 2;                 // A staging: col within k-tile
  float acc[RM][8] = {};
  float4 av[RM / 2], avn[RM / 2];

#pragma unroll
  for (int n = 0; n < RM / 2; n++) {
    int r = (tid >> 3) + n * 32;
    av[n] = make_float4(0.f, 0.f, 0.f, 0.f);
    if (row0 + r < NN) av[n] = *(const float4*)(A + (size_t)(row0 + r) * K + kc_a);
  }

#pragma unroll
  for (int kb = 0; kb < K; kb += 32) {
    float4 bv[4];
#pragma unroll
    for (int n = 0; n < 4; n++) {
      int idx = tid + (n << 8);
      int rb = idx >> 5, c4 = (idx & 31) << 2;
      bv[n] = *(const float4*)(WB + (size_t)(kb + rb) * 256 + c4);
    }
    if (kb) __syncthreads();
#pragma unroll
    for (int n = 0; n < RM / 2; n++) {
      int r = (tid >> 3) + n * 32;
      As[kc_a + 0][r] = av[n].x; As[kc_a + 1][r] = av[n].y;
      As[kc_a + 2][r] = av[n].z; As[kc_a + 3][r] = av[n].w;
    }
#pragma unroll
    for (int n = 0; n < 4; n++) {
      int idx = tid + (n << 8);
      int rb = idx >> 5, c4 = (idx & 31) << 2;
      *(float4*)&Bs[rb][c4] = bv[n];
    }
    __syncthreads();
    if (kb + 32 < K) {
#pragma unroll
      for (int n = 0; n < RM / 2; n++) {
        int r = (tid >> 3) + n * 32;
        avn[n] = make_float4(0.f, 0.f, 0.f, 0.f);
        if (row0 + r < NN)
          avn[n] = *(const float4*)(A + (size_t)(row0 + r) * K + kb + 32 + kc_a);
      }
    }
#pragma unroll 2
    for (int k = 0; k < 32; k++) {
      float a0[4], a1[4], bb[8];
      *(float4*)a0 = *(const float4*)&As[k][ra << 2];
      if (RM == 8) *(float4*)a1 = *(const float4*)&As[k][64 + (ra << 2)];
      *(float4*)(bb)     = *(const float4*)&Bs[k][tx << 2];
      *(float4*)(bb + 4) = *(const float4*)&Bs[k][64 + (tx << 2)];
#pragma unroll
      for (int i = 0; i < 4; i++)
#pragma unroll
        for (int j = 0; j < 8; j++) {
          acc[i][j] = fmaf(a0[i], bb[j], acc[i][j]);
          if (RM == 8) acc[4 + i][j] = fmaf(a1[i], bb[j], acc[4 + i][j]);
        }
    }
#pragma unroll
    for (int n = 0; n < RM / 2; n++) av[n] = avn[n];
  }

  float asr[8], adr[8];
#pragma unroll
  for (int j = 0; j < 4; j++) {
    asr[j]     = a_s[gc0 + (tx << 2) + j];
    asr[j + 4] = a_s[gc0 + 64 + (tx << 2) + j];
    adr[j]     = a_d[gc0 + (tx << 2) + j];
    adr[j + 4] = a_d[gc0 + 64 + (tx << 2) + j];
  }
  int slot0 = gc0 >> 6, slot1 = (gc0 + 64) >> 6;
#pragma unroll
  for (int i = 0; i < RM; i++) {
    int lr = (i < 4) ? ((ra << 2) + i) : (64 + (ra << 2) + (i - 4));
    int gr = row0 + lr;
    float ps0 = 0.f, pd0 = 0.f, ps1 = 0.f, pd1 = 0.f;
#pragma unroll
    for (int j = 0; j < 4; j++) {
      ps0 = fmaf(acc[i][j], asr[j], ps0);
      pd0 = fmaf(acc[i][j], adr[j], pd0);
      ps1 = fmaf(acc[i][j + 4], asr[j + 4], ps1);
      pd1 = fmaf(acc[i][j + 4], adr[j + 4], pd1);
    }
#pragma unroll
    for (int m = 1; m < 16; m <<= 1) {
      ps0 += __shfl_xor(ps0, m); pd0 += __shfl_xor(pd0, m);
      ps1 += __shfl_xor(ps1, m); pd1 += __shfl_xor(pd1, m);
    }
    if (gr < NN) {
      *(float4*)(H + (size_t)gr * hstride + hcolb + (tx << 2)) =
          make_float4(acc[i][0], acc[i][1], acc[i][2], acc[i][3]);
      *(float4*)(H + (size_t)gr * hstride + hcolb + 64 + (tx << 2)) =
          make_float4(acc[i][4], acc[i][5], acc[i][6], acc[i][7]);
      if (tx == 0) {
        asrc[(size_t)gr * 16 + slot0] = ps0;
        asrc[(size_t)gr * 16 + slot1] = ps1;
        adst[(size_t)gr * 16 + slot0] = pd0;
        adst[(size_t)gr * 16 + slot1] = pd1;
      }
    }
  }
}

// ---------------- fused aggregation v3: block = 1 node, wave = 1 edge type ----
// Edge list padded to a multiple of 8 with zero-weight dummies; pass B issues
// 8 global_load_dwordx4 per batch (no tail) via wave-uniform base + u32 offsets.
template <bool FINAL>
__global__ __launch_bounds__(256) void k_agg3(
    const int* __restrict__ rp, const int* __restrict__ col,
    const float* __restrict__ asrc, const float* __restrict__ adst,
    const float* __restrict__ h, const float* __restrict__ bias,
    float* __restrict__ xout, const float* __restrict__ linW,
    const float* __restrict__ linb, int hstride) {
  __shared__ float wl[4][DCAP * 4];
  __shared__ int scol[4][DCAP];
  __shared__ float sbuf[4][64];
  __shared__ float xv[64];
  int v = blockIdx.x;
  int tid = threadIdx.x;
  int t = tid >> 6, lane = tid & 63;
  const int* rpt = rp + t * RP_STRIDE;
  const int* colt = col + (size_t)t * EPN;
  int beg = rpt[v];
  int deg = rpt[v + 1] - beg;
  int hq = lane >> 4, il = lane & 15;
  int slot = (t << 2) + hq;
  float adv = adst[(size_t)v * 16 + slot];
  float f0 = 0.f, f1 = 0.f, f2 = 0.f, f3 = 0.f;
  float rz;

  if (deg <= DCAP) {
    int dpad = (deg + 7) & ~7;
    // pass A: e -> LDS, running max
    float m = -1e30f;
    for (int i = il; i < deg; i += 16) {
      int s = colt[beg + i];
      float e = asrc[(unsigned)(s * 16 + slot)] + adv;
      e = e > 0.f ? e : 0.2f * e;
      wl[t][(i << 2) + hq] = e;
      if (hq == 0) scol[t][i] = s;
      m = fmaxf(m, e);
    }
    m = fmaxf(m, __shfl_xor(m, 1)); m = fmaxf(m, __shfl_xor(m, 2));
    m = fmaxf(m, __shfl_xor(m, 4)); m = fmaxf(m, __shfl_xor(m, 8));
    // exp pass (LDS-local) + zero-weight padding
    float z = 0.f;
    for (int i = il; i < deg; i += 16) {
      float w = __expf(wl[t][(i << 2) + hq] - m);
      wl[t][(i << 2) + hq] = w;
      z += w;
    }
    for (int i = deg + il; i < dpad; i += 16) {
      wl[t][(i << 2) + hq] = 0.f;
      if (hq == 0) scol[t][i] = colt[beg];
    }
    z += __shfl_xor(z, 1); z += __shfl_xor(z, 2);
    z += __shfl_xor(z, 4); z += __shfl_xor(z, 8);
    rz = 1.f / z;
    // pass B: batches of 8 gathers in flight
    const float* hbase = h + (t << 8);            // wave-uniform
    unsigned lb = (unsigned)(lane << 2);
    unsigned hs = (unsigned)hstride;
    for (int i = 0; i < dpad; i += 8) {
      unsigned soff[8];
      float4 hv[8];
      float wv[8];
#pragma unroll
      for (int u = 0; u < 8; u++)
        soff[u] = (unsigned)scol[t][i + u] * hs + lb;
#pragma unroll
      for (int u = 0; u < 8; u++)
        hv[u] = *(const float4*)(hbase + soff[u]);
#pragma unroll
      for (int u = 0; u < 8; u++)
        wv[u] = wl[t][((i + u) << 2) + hq];
#pragma unroll
      for (int u = 0; u < 8; u++) {
        f0 = fmaf(wv[u], hv[u].x, f0); f1 = fmaf(wv[u], hv[u].y, f1);
        f2 = fmaf(wv[u], hv[u].z, f2); f3 = fmaf(wv[u], hv[u].w, f3);
      }
    }
  } else {
    // slow path: 3-pass recompute (wave-uniform branch, deg unbounded)
    const float* hb = h + (t << 8) + (lane << 2);
    float m = -1e30f;
    for (int i = il; i < deg; i += 16) {
      int s = colt[beg + i];
      float e = asrc[(size_t)s * 16 + slot] + adv;
      e = e > 0.f ? e : 0.2f * e;
      m = fmaxf(m, e);
    }
    m = fmaxf(m, __shfl_xor(m, 1)); m = fmaxf(m, __shfl_xor(m, 2));
    m = fmaxf(m, __shfl_xor(m, 4)); m = fmaxf(m, __shfl_xor(m, 8));
    float z = 0.f;
    for (int i = il; i < deg; i += 16) {
      int s = colt[beg + i];
      float e = asrc[(size_t)s * 16 + slot] + adv;
      e = e > 0.f ? e : 0.2f * e;
      z += __expf(e - m);
    }
    z += __shfl_xor(z, 1); z += __shfl_xor(z, 2);
    z += __shfl_xor(z, 4); z += __shfl_xor(z, 8);
    rz = 1.f / z;
    for (int i = 0; i < deg; i++) {
      int s = colt[beg + i];
      float e = asrc[(size_t)s * 16 + slot] + adv;
      e = e > 0.f ? e : 0.2f * e;
      float w = __expf(e - m);
      float4 hv = *(const float4*)(hb + (size_t)s * hstride);
      f0 = fmaf(w, hv.x, f0); f1 = fmaf(w, hv.y, f1);
      f2 = fmaf(w, hv.z, f2); f3 = fmaf(w, hv.w, f3);
    }
  }
  f0 *= rz; f1 *= rz; f2 *= rz; f3 *= rz;
  // head mean (sum over the 4 16-lane head groups)
  f0 += __shfl_xor(f0, 16); f0 += __shfl_xor(f0, 32);
  f1 += __shfl_xor(f1, 16); f1 += __shfl_xor(f1, 32);
  f2 += __shfl_xor(f2, 16); f2 += __shfl_xor(f2, 32);
  f3 += __shfl_xor(f3, 16); f3 += __shfl_xor(f3, 32);
  int c = il << 2;
  if (lane < 16) {
    sbuf[t][c + 0] = f0 * 0.25f + bias[(t << 6) + c + 0];
    sbuf[t][c + 1] = f1 * 0.25f + bias[(t << 6) + c + 1];
    sbuf[t][c + 2] = f2 * 0.25f + bias[(t << 6) + c + 2];
    sbuf[t][c + 3] = f3 * 0.25f + bias[(t << 6) + c + 3];
  }
  __syncthreads();
  if (FINAL) {
    if (tid < 64)
      xv[tid] = fmaxf((sbuf[0][tid] + sbuf[1][tid] + sbuf[2][tid] + sbuf[3][tid]) * 0.25f, 0.f);
    __syncthreads();
    if (tid < 32) {
      float accv = linb[tid];
#pragma unroll
      for (int cc = 0; cc < 64; cc++) accv = fmaf(xv[cc], linW[cc * 32 + tid], accv);
      xout[(size_t)v * 32 + tid] = accv;
    }
  } else {
    if (tid < 64)
      xout[(size_t)v * 64 + tid] =
          fmaxf((sbuf[0][tid] + sbuf[1][tid] + sbuf[2][tid] + sbuf[3][tid]) * 0.25f, 0.f);
  }
}

// ---------------- per-type fallback aggregation: wave = 1 node ----------------
__global__ __launch_bounds__(256) void k_agg_pt(
    const int* __restrict__ rp, const int* __restrict__ col,
    const float* __restrict__ asrc, const float* __restrict__ adst,
    const float* __restrict__ h, const float* __restrict__ bias,
    float* __restrict__ accum, int slotbase) {
  int v = blockIdx.x * 4 + (threadIdx.x >> 6);
  int lane = threadIdx.x & 63;
  if (v >= NN) return;
  int slot = slotbase + (lane >> 4);
  int beg = rp[v];
  int deg = rp[v + 1] - beg;
  float adv = adst[(size_t)v * 16 + slot];
  float m = -1e30f;
  for (int i = lane & 15; i < deg; i += 16) {
    int s = col[beg + i];
    float e = asrc[(size_t)s * 16 + slot] + adv;
    e = e > 0.f ? e : 0.2f * e;
    m = fmaxf(m, e);
  }
  m = fmaxf(m, __shfl_xor(m, 1)); m = fmaxf(m, __shfl_xor(m, 2));
  m = fmaxf(m, __shfl_xor(m, 4)); m = fmaxf(m, __shfl_xor(m, 8));
  float z = 0.f;
  for (int i = lane & 15; i < deg; i += 16) {
    int s = col[beg + i];
    float e = asrc[(size_t)s * 16 + slot] + adv;
    e = e > 0.f ? e : 0.2f * e;
    z += __expf(e - m);
  }
  z += __shfl_xor(z, 1); z += __shfl_xor(z, 2);
  z += __shfl_xor(z, 4); z += __shfl_xor(z, 8);
  float rz = 1.f / z;
  float f0 = 0.f, f1 = 0.f, f2 = 0.f, f3 = 0.f;
  const float* hb = h + (lane << 2);
#pragma unroll 2
  for (int i = 0; i < deg; i++) {
    int s = col[beg + i];
    float e = asrc[(size_t)s * 16 + slot] + adv;
    e = e > 0.f ? e : 0.2f * e;
    float w = __expf(e - m) * rz;
    float4 hv = *(const float4*)(hb + (size_t)s * 256);
    f0 = fmaf(w, hv.x, f0); f1 = fmaf(w, hv.y, f1);
    f2 = fmaf(w, hv.z, f2); f3 = fmaf(w, hv.w, f3);
  }
  f0 += __shfl_xor(f0, 16); f0 += __shfl_xor(f0, 32);
  f1 += __shfl_xor(f1, 16); f1 += __shfl_xor(f1, 32);
  f2 += __shfl_xor(f2, 16); f2 += __shfl_xor(f2, 32);
  f3 += __shfl_xor(f3, 16); f3 += __shfl_xor(f3, 32);
  int c = (lane & 15) << 2;
  if (lane < 16) {
    float* ap = accum + (size_t)v * 64 + c;
    ap[0] += f0 * 0.25f + bias[c + 0];
    ap[1] += f1 * 0.25f + bias[c + 1];
    ap[2] += f2 * 0.25f + bias[c + 2];
    ap[3] += f3 * 0.25f + bias[c + 3];
  }
}

__global__ void k_finalize(const float* __restrict__ accum, float* __restrict__ xout) {
  int i = blockIdx.x * blockDim.x + threadIdx.x;
  if (i < NN * NC) xout[i] = fmaxf(accum[i] * 0.25f, 0.f);
}

__global__ void k_linear(const float* __restrict__ x, const float* __restrict__ W,
                         const float* __restrict__ b, float* __restrict__ out) {
  int i = blockIdx.x * blockDim.x + threadIdx.x;
  if (i >= NN * 32) return;
  int v = i >> 5, o = i & 31;
  float acc = b[o];
#pragma unroll
  for (int c = 0; c < 64; c++) acc = fmaf(x[v * 64 + c], W[c * 32 + o], acc);
  out[i] = acc;
}

extern "C" void kernel_launch(void* const* d_in, const int* in_sizes, int n_in,
                              void* d_out, int out_size, void* d_ws, size_t ws_size,
                              hipStream_t stream) {
  const float* x = (const float*)d_in[0];
  const int* e0 = (const int*)d_in[1];
  const int* e1 = (const int*)d_in[2];
  const int* e2 = (const int*)d_in[3];
  const int* e3 = (const int*)d_in[4];
  const float* Wl[2]  = {(const float*)d_in[5], (const float*)d_in[9]};
  const float* asl[2] = {(const float*)d_in[6], (const float*)d_in[10]};
  const float* adl[2] = {(const float*)d_in[7], (const float*)d_in[11]};
  const float* bl[2]  = {(const float*)d_in[8], (const float*)d_in[12]};
  const float* linW = (const float*)d_in[13];
  const float* linb = (const float*)d_in[14];
  float* out = (float*)d_out;
  (void)in_sizes; (void)n_in; (void)out_size;

  bool fused = ws_size >= (size_t)98 * 1024 * 1024;

  char* wsb = (char*)d_ws;
  size_t off = 0;
  auto carve = [&](size_t bytes) -> char* {
    off = (off + 255) & ~(size_t)255;
    char* p = wsb + off;
    off += bytes;
    return p;
  };
  int* cnt    = (int*)carve((size_t)4 * NN * sizeof(int));
  int* tmp    = (int*)carve((size_t)4 * NN * sizeof(int));
  int* rp     = (int*)carve((size_t)4 * RP_STRIDE * sizeof(int));
  int* col    = (int*)carve((size_t)4 * EPN * sizeof(int));
  float* asrc = (float*)carve((size_t)NN * 16 * sizeof(float));
  float* adst = (float*)carve((size_t)NN * 16 * sizeof(float));
  float* h    = (float*)carve((size_t)NN * (fused ? 1024 : 256) * sizeof(float));
  float* xmid = (float*)carve((size_t)NN * NC * sizeof(float));
  float* accum = fused ? nullptr : (float*)carve((size_t)NN * NC * sizeof(float));

  // CSR build (edges identical across layers -> build once per call)
  k_init_counts<<<(4 * NN + 255) / 256, 256, 0, stream>>>(cnt);
  k_count<<<(4 * NE + 255) / 256, 256, 0, stream>>>(e0 + NE, e1 + NE, e2 + NE, e3 + NE, cnt);
  k_scan<<<4, 256, 0, stream>>>(cnt, rp, tmp);
  k_fill<<<(4 * EPN + 255) / 256, 256, 0, stream>>>(e0, e1, e2, e3, tmp, col);

  if (fused) {
    const int GBX = (NN + 127) / 128;
    // layer 0
    k_gemm_attn<128, 8><<<dim3(GBX, 8), 256, 0, stream>>>(
        x, Wl[0], asl[0], adl[0], h, asrc, adst, 0, 1024);
    k_agg3<false><<<NN, 256, 0, stream>>>(
        rp, col, asrc, adst, h, bl[0], xmid, nullptr, nullptr, 1024);
    // layer 1 + final linear
    k_gemm_attn<64, 8><<<dim3(GBX, 8), 256, 0, stream>>>(
        xmid, Wl[1], asl[1], adl[1], h, asrc, adst, 0, 1024);
    k_agg3<true><<<NN, 256, 0, stream>>>(
        rp, col, asrc, adst, h, bl[1], out, linW, linb, 1024);
  } else {
    const int GBX = (NN + 63) / 64;
    for (int l = 0; l < 2; l++) {
      const float* xin = (l == 0) ? x : xmid;
      hipMemsetAsync(accum, 0, (size_t)NN * NC * sizeof(float), stream);
      for (int t = 0; t < 4; t++) {
        if (l == 0)
          k_gemm_attn<128, 4><<<dim3(GBX, 2), 256, 0, stream>>>(
              xin, Wl[l], asl[l], adl[l], h, asrc, adst, t * 256, 256);
        else
          k_gemm_attn<64, 4><<<dim3(GBX, 2), 256, 0, stream>>>(
              xin, Wl[l], asl[l], adl[l], h, asrc, adst, t * 256, 256);
        k_agg_pt<<<(NN + 3) / 4, 256, 0, stream>>>(
            rp + t * RP_STRIDE, col + (size_t)t * EPN, asrc, adst, h,
            bl[l] + t * NC, accum, t * 4);
      }
      k_finalize<<<(NN * NC + 255) / 256, 256, 0, stream>>>(accum, xmid);
    }
    k_linear<<<(NN * 32 + 255) / 256, 256, 0, stream>>>(xmid, linW, linb, out);
  }
}